// Round 1
// baseline (242.085 us; speedup 1.0000x reference)
//
#include <hip/hip_runtime.h>
#include <hip/hip_bf16.h>

typedef __attribute__((ext_vector_type(8))) short   bf16x8;
typedef __attribute__((ext_vector_type(4))) float   f32x4;
typedef __attribute__((ext_vector_type(4))) unsigned short u16x4;
typedef unsigned short u16;

#define NTOK 64
#define CEMB 192
#define NH   6
#define PADC 200   // padded row length (bf16 elems) for [64][*] tiles -> 400B rows
#define VPAD 72    // padded key-dim for vhT / P tiles -> 144B rows

__device__ __forceinline__ u16 f2b(float f) {
  unsigned u = __float_as_uint(f);
  unsigned r = (u + 0x7fffu + ((u >> 16) & 1u)) >> 16;  // RNE
  return (u16)r;
}

// ---------------- prep: pack W^T (bf16) + gather rel_bias ----------------
__global__ void prep_kernel(const float* __restrict__ Wq, const float* __restrict__ Wk,
                            const float* __restrict__ Wv, const float* __restrict__ Wp,
                            const float* __restrict__ btab, const int* __restrict__ ridx,
                            u16* __restrict__ WT, float* __restrict__ rb) {
  int idx = blockIdx.x * 256 + threadIdx.x;
  if (idx < 4 * 36864) {
    int m = idx / 36864;
    int e = idx - m * 36864;
    int n = e / CEMB;
    int k = e - n * CEMB;
    const float* W = (m == 0) ? Wq : (m == 1) ? Wk : (m == 2) ? Wv : Wp;
    WT[idx] = f2b(W[k * CEMB + n]);          // WT[m][n][k] = W[k][n]
  } else {
    int i2 = idx - 4 * 36864;
    if (i2 < NH * 4096) {
      int h = i2 >> 12;
      int ij = i2 & 4095;
      rb[i2] = btab[ridx[ij] * NH + h];      // rb[h][i][j]
    }
  }
}

// ---------------- fused window attention ----------------
__global__ __launch_bounds__(512, 2)
void wattn_kernel(const float* __restrict__ qg, const float* __restrict__ kg,
                  const float* __restrict__ vg, const float* __restrict__ maskg,
                  const float* __restrict__ bq, const float* __restrict__ bk,
                  const float* __restrict__ bv, const float* __restrict__ bp,
                  const u16* __restrict__ WT, const float* __restrict__ rb,
                  float* __restrict__ xout, float* __restrict__ attn_out) {
  __shared__ u16 sQ[NTOK * PADC];      // q stage -> qh
  __shared__ u16 sK[NTOK * PADC];      // k stage -> kh
  __shared__ u16 sV[CEMB * VPAD];      // v stage ([64][PADC], fits) -> vhT [192][72]
  __shared__ u16 sX[NTOK * PADC];      // attention output x (bf16)
  __shared__ u16 sP[8 * 16 * VPAD];    // per-wave P scratch [16][72]

  const int tid  = threadIdx.x;
  const int wave = tid >> 6;
  const int lane = tid & 63;
  const int l15  = lane & 15;
  const int lhi  = lane >> 4;          // 0..3
  const int b    = blockIdx.x;
  const float scale = 0.17677669529663687f;   // 32^-0.5

  // ---- Phase 1: stage q,k,v fp32 -> bf16 LDS (padded rows) ----
  {
    const size_t base = (size_t)b * NTOK * CEMB;
    #pragma unroll
    for (int m = 0; m < 3; ++m) {
      const float* src = (m == 0 ? qg : m == 1 ? kg : vg) + base;
      u16* dst = (m == 0 ? sQ : m == 1 ? sK : sV);
      #pragma unroll
      for (int it = 0; it < 6; ++it) {
        int fi  = it * 512 + tid;            // float4 index, 0..3071
        int row = fi / 48;                   // 48 float4 per row of 192
        int c4  = (fi - row * 48) * 4;
        const float4 v4 = reinterpret_cast<const float4*>(src)[fi];
        u16x4 p;
        p.x = f2b(v4.x); p.y = f2b(v4.y); p.z = f2b(v4.z); p.w = f2b(v4.w);
        *reinterpret_cast<u16x4*>(&dst[row * PADC + c4]) = p;
      }
    }
  }
  __syncthreads();

  // ---- Phase 2: QKV projections. 36 col-strips (3 matrices x 12 ct), B-frag reused over 4 row tiles ----
  f32x4 accv[5][4];
  #pragma unroll
  for (int si = 0; si < 5; ++si) {
    int strip = wave + si * 8;
    if (strip < 36) {
      int m  = strip / 12;
      int ct = strip - m * 12;
      const u16* Xs = (m == 0) ? sQ : (m == 1) ? sK : sV;
      const u16* Wt = WT + m * 36864 + (ct * 16 + l15) * CEMB + lhi * 8;
      f32x4 z = {0.f, 0.f, 0.f, 0.f};
      #pragma unroll
      for (int rt = 0; rt < 4; ++rt) accv[si][rt] = z;
      #pragma unroll
      for (int ks = 0; ks < 6; ++ks) {
        bf16x8 bw = *reinterpret_cast<const bf16x8*>(Wt + ks * 32);
        #pragma unroll
        for (int rt = 0; rt < 4; ++rt) {
          bf16x8 ax = *reinterpret_cast<const bf16x8*>(&Xs[(rt * 16 + l15) * PADC + ks * 32 + lhi * 8]);
          accv[si][rt] = __builtin_amdgcn_mfma_f32_16x16x32_bf16(ax, bw, accv[si][rt], 0, 0, 0);
        }
      }
    }
  }
  __syncthreads();   // all reads of staged q,k,v done

  #pragma unroll
  for (int si = 0; si < 5; ++si) {
    int strip = wave + si * 8;
    if (strip < 36) {
      int m  = strip / 12;
      int ct = strip - m * 12;
      int n  = ct * 16 + l15;
      float bval = ((m == 0) ? bq : (m == 1) ? bk : bv)[n];
      if (m == 0) {
        #pragma unroll
        for (int rt = 0; rt < 4; ++rt)
          #pragma unroll
          for (int r = 0; r < 4; ++r)
            sQ[(rt * 16 + lhi * 4 + r) * PADC + n] = f2b((accv[si][rt][r] + bval) * scale);
      } else if (m == 1) {
        #pragma unroll
        for (int rt = 0; rt < 4; ++rt)
          #pragma unroll
          for (int r = 0; r < 4; ++r)
            sK[(rt * 16 + lhi * 4 + r) * PADC + n] = f2b(accv[si][rt][r] + bval);
      } else {   // vhT[chan n][key]
        #pragma unroll
        for (int rt = 0; rt < 4; ++rt)
          #pragma unroll
          for (int r = 0; r < 4; ++r)
            sV[n * VPAD + rt * 16 + lhi * 4 + r] = f2b(accv[si][rt][r] + bval);
      }
    }
  }
  __syncthreads();   // qh/kh/vhT ready

  // ---- Phase 3: per (head, row-tile) unit: S -> softmax -> attn store -> PV -> sX ----
  const float* maskw = maskg + (size_t)(b & 1023) * 4096;
  u16* pw = sP + wave * 16 * VPAD;
  #pragma unroll
  for (int ui = 0; ui < 3; ++ui) {
    int u  = wave + ui * 8;        // 0..23
    int h  = u >> 2;
    int rt = u & 3;
    int irow = rt * 16 + lhi * 4;  // + r

    // S = qh @ kh^T  (K = 32, one MFMA per col tile)
    bf16x8 aq = *reinterpret_cast<const bf16x8*>(&sQ[(rt * 16 + l15) * PADC + h * 32 + lhi * 8]);
    f32x4 sv[4];
    #pragma unroll
    for (int ct = 0; ct < 4; ++ct) {
      bf16x8 bkf = *reinterpret_cast<const bf16x8*>(&sK[(ct * 16 + l15) * PADC + h * 32 + lhi * 8]);
      f32x4 z = {0.f, 0.f, 0.f, 0.f};
      sv[ct] = __builtin_amdgcn_mfma_f32_16x16x32_bf16(aq, bkf, z, 0, 0, 0);
    }

    // logits = S + rel_bias + mask
    const float* rbp = rb + h * 4096 + irow * 64 + l15;
    const float* mkp = maskw + irow * 64 + l15;
    float lg[4][4];
    #pragma unroll
    for (int ct = 0; ct < 4; ++ct)
      #pragma unroll
      for (int r = 0; r < 4; ++r)
        lg[ct][r] = sv[ct][r] + rbp[r * 64 + ct * 16] + mkp[r * 64 + ct * 16];

    // row softmax (row lives in 16 lanes x 4 ct values)
    float pr[4][4];
    #pragma unroll
    for (int r = 0; r < 4; ++r) {
      float mx = fmaxf(fmaxf(lg[0][r], lg[1][r]), fmaxf(lg[2][r], lg[3][r]));
      mx = fmaxf(mx, __shfl_xor(mx, 1));
      mx = fmaxf(mx, __shfl_xor(mx, 2));
      mx = fmaxf(mx, __shfl_xor(mx, 4));
      mx = fmaxf(mx, __shfl_xor(mx, 8));
      float e0 = __expf(lg[0][r] - mx), e1 = __expf(lg[1][r] - mx);
      float e2 = __expf(lg[2][r] - mx), e3 = __expf(lg[3][r] - mx);
      float sum = e0 + e1 + e2 + e3;
      sum += __shfl_xor(sum, 1);
      sum += __shfl_xor(sum, 2);
      sum += __shfl_xor(sum, 4);
      sum += __shfl_xor(sum, 8);
      float inv = 1.0f / sum;
      pr[0][r] = e0 * inv; pr[1][r] = e1 * inv; pr[2][r] = e2 * inv; pr[3][r] = e3 * inv;
    }

    // store attn (fp32 global) + P (bf16, per-wave LDS)
    float* ap = attn_out + (((size_t)b * NH + h) * NTOK + irow) * NTOK;
    #pragma unroll
    for (int ct = 0; ct < 4; ++ct)
      #pragma unroll
      for (int r = 0; r < 4; ++r) {
        ap[r * 64 + ct * 16 + l15] = pr[ct][r];
        pw[(lhi * 4 + r) * VPAD + ct * 16 + l15] = f2b(pr[ct][r]);
      }

    // PV: x[16 rows][32 cols of head h] = P @ vh  (K = 64 -> 2 k-steps)
    f32x4 xa[2];
    {
      f32x4 z = {0.f, 0.f, 0.f, 0.f};
      xa[0] = z; xa[1] = z;
    }
    #pragma unroll
    for (int ks = 0; ks < 2; ++ks) {
      bf16x8 apf = *reinterpret_cast<const bf16x8*>(&pw[l15 * VPAD + ks * 32 + lhi * 8]);
      #pragma unroll
      for (int ctv = 0; ctv < 2; ++ctv) {
        bf16x8 bvf = *reinterpret_cast<const bf16x8*>(&sV[(h * 32 + ctv * 16 + l15) * VPAD + ks * 32 + lhi * 8]);
        xa[ctv] = __builtin_amdgcn_mfma_f32_16x16x32_bf16(apf, bvf, xa[ctv], 0, 0, 0);
      }
    }
    #pragma unroll
    for (int ctv = 0; ctv < 2; ++ctv)
      #pragma unroll
      for (int r = 0; r < 4; ++r)
        sX[(rt * 16 + lhi * 4 + r) * PADC + h * 32 + ctv * 16 + l15] = f2b(xa[ctv][r]);
  }
  __syncthreads();   // sX complete

  // ---- Phase 4: out = x @ Wp + bp.  24 units = 12 ct x 2 row-halves ----
  #pragma unroll
  for (int ui = 0; ui < 3; ++ui) {
    int u2 = wave + ui * 8;        // 0..23
    int ct = u2 % 12;
    int rh = u2 / 12;
    const u16* Wt = WT + 3 * 36864 + (ct * 16 + l15) * CEMB + lhi * 8;
    f32x4 oa[2];
    {
      f32x4 z = {0.f, 0.f, 0.f, 0.f};
      oa[0] = z; oa[1] = z;
    }
    #pragma unroll
    for (int ks = 0; ks < 6; ++ks) {
      bf16x8 bw = *reinterpret_cast<const bf16x8*>(Wt + ks * 32);
      #pragma unroll
      for (int rr = 0; rr < 2; ++rr) {
        bf16x8 ax = *reinterpret_cast<const bf16x8*>(&sX[(rh * 32 + rr * 16 + l15) * PADC + ks * 32 + lhi * 8]);
        oa[rr] = __builtin_amdgcn_mfma_f32_16x16x32_bf16(ax, bw, oa[rr], 0, 0, 0);
      }
    }
    float bias = bp[ct * 16 + l15];
    #pragma unroll
    for (int rr = 0; rr < 2; ++rr)
      #pragma unroll
      for (int r = 0; r < 4; ++r)
        xout[((size_t)b * NTOK + rh * 32 + rr * 16 + lhi * 4 + r) * CEMB + ct * 16 + l15] = oa[rr][r] + bias;
  }
}

extern "C" void kernel_launch(void* const* d_in, const int* in_sizes, int n_in,
                              void* d_out, int out_size, void* d_ws, size_t ws_size,
                              hipStream_t stream) {
  const float* q    = (const float*)d_in[0];
  const float* k    = (const float*)d_in[1];
  const float* v    = (const float*)d_in[2];
  const float* mask = (const float*)d_in[3];
  const float* Wq   = (const float*)d_in[4];
  const float* bq   = (const float*)d_in[5];
  const float* Wk   = (const float*)d_in[6];
  const float* bk   = (const float*)d_in[7];
  const float* Wv   = (const float*)d_in[8];
  const float* bv   = (const float*)d_in[9];
  const float* Wp   = (const float*)d_in[10];
  const float* bp   = (const float*)d_in[11];
  const float* btab = (const float*)d_in[12];
  const int*   ridx = (const int*)d_in[13];

  u16*   WT = (u16*)d_ws;                               // 4 * 36864 bf16 = 294912 B
  float* rb = (float*)((char*)d_ws + 4 * 36864 * 2);    // 6*64*64 fp32 = 98304 B

  float* xout = (float*)d_out;
  float* attn = xout + (size_t)2048 * NTOK * CEMB;

  prep_kernel<<<672, 256, 0, stream>>>(Wq, Wk, Wv, Wp, btab, ridx, WT, rb);
  wattn_kernel<<<2048, 512, 0, stream>>>(q, k, v, mask, bq, bk, bv, bp, WT, rb, xout, attn);
}

// Round 2
// 221.445 us; speedup vs baseline: 1.0932x; 1.0932x over previous
//
#include <hip/hip_runtime.h>
#include <hip/hip_bf16.h>

typedef __attribute__((ext_vector_type(8))) short   bf16x8;
typedef __attribute__((ext_vector_type(4))) float   f32x4;
typedef __attribute__((ext_vector_type(4))) unsigned short u16x4;
typedef unsigned short u16;

#define NTOK 64
#define CEMB 192
#define NH   6
#define ROWB 384   // row bytes for [64][192] bf16 tiles (sQ/sK/staged V/X)
#define VROWB 128  // row bytes for vhT [192][64] bf16

__device__ __forceinline__ u16 f2b(float f) {
  unsigned u = __float_as_uint(f);
  unsigned r = (u + 0x7fffu + ((u >> 16) & 1u)) >> 16;  // RNE
  return (u16)r;
}

// XOR swizzle on bits 4-6 of the column byte offset; key mixes row bits 0-3
// so that 16 consecutive rows hit 8 distinct 16B slots (2-way = free) and the
// scattered b16 epilogue writes (rows {r,4+r,8+r,12+r}) hit 4 distinct slots.
__device__ __forceinline__ int swz(int row, int colbyte) {
  return colbyte ^ ((((row >> 3) ^ row) & 7) << 4);
}

// ---------------- prep: pack W^T (bf16) + gather rel_bias ----------------
__global__ void prep_kernel(const float* __restrict__ Wq, const float* __restrict__ Wk,
                            const float* __restrict__ Wv, const float* __restrict__ Wp,
                            const float* __restrict__ btab, const int* __restrict__ ridx,
                            u16* __restrict__ WT, float* __restrict__ rb) {
  int idx = blockIdx.x * 256 + threadIdx.x;
  if (idx < 4 * 36864) {
    int m = idx / 36864;
    int e = idx - m * 36864;
    int n = e / CEMB;
    int k = e - n * CEMB;
    const float* W = (m == 0) ? Wq : (m == 1) ? Wk : (m == 2) ? Wv : Wp;
    WT[idx] = f2b(W[k * CEMB + n]);          // WT[m][n][k] = W[k][n]
  } else {
    int i2 = idx - 4 * 36864;
    if (i2 < NH * 4096) {
      int h = i2 >> 12;
      int ij = i2 & 4095;
      rb[i2] = btab[ridx[ij] * NH + h];      // rb[h][i][j]
    }
  }
}

// ---------------- fused window attention ----------------
__global__ __launch_bounds__(512, 4)
void wattn_kernel(const float* __restrict__ qg, const float* __restrict__ kg,
                  const float* __restrict__ vg, const float* __restrict__ maskg,
                  const float* __restrict__ bq, const float* __restrict__ bk,
                  const float* __restrict__ bv, const float* __restrict__ bp,
                  const u16* __restrict__ WT, const float* __restrict__ rb,
                  float* __restrict__ xout, float* __restrict__ attn_out) {
  // 80 KB total -> 2 blocks/CU
  __shared__ __align__(16) char smem[81920];
  char* sQ = smem;                 // [64][192] q-stage -> qh -> X (in-place)
  char* sK = smem + 24576;         // [64][192] k-stage -> kh
  char* sV = smem + 49152;         // [64][192] v-stage -> vhT [192][64]
  const int tid  = threadIdx.x;
  const int wave = tid >> 6;
  const int lane = tid & 63;
  const int l15  = lane & 15;
  const int lhi  = lane >> 4;          // 0..3
  char* sP = smem + 73728 + wave * 1024;  // per-wave P transpose scratch (half tile)
  const int b    = blockIdx.x;
  const float scale = 0.17677669529663687f;   // 32^-0.5

  // ---- Phase 1: stage q,k,v fp32 -> bf16 LDS (swizzled) ----
  {
    const size_t base = (size_t)b * NTOK * CEMB;
    #pragma unroll
    for (int m = 0; m < 3; ++m) {
      const float* src = (m == 0 ? qg : m == 1 ? kg : vg) + base;
      char* dst = (m == 0 ? sQ : m == 1 ? sK : sV);
      #pragma unroll
      for (int it = 0; it < 6; ++it) {
        int fi  = it * 512 + tid;            // float4 index, 0..3071
        int row = fi / 48;                   // 48 float4 per row of 192
        int ce  = (fi - row * 48) * 4;       // element col
        const float4 v4 = reinterpret_cast<const float4*>(src)[fi];
        u16x4 p;
        p.x = f2b(v4.x); p.y = f2b(v4.y); p.z = f2b(v4.z); p.w = f2b(v4.w);
        *reinterpret_cast<u16x4*>(dst + row * ROWB + swz(row, ce * 2)) = p;
      }
    }
  }
  __syncthreads();

  // ---- Phase 2: QKV projections. 36 col-strips (3 matrices x 12 ct) ----
  f32x4 accv[5][4];
  #pragma unroll
  for (int si = 0; si < 5; ++si) {
    int strip = wave + si * 8;
    if (strip < 36) {
      int m  = strip / 12;
      int ct = strip - m * 12;
      const char* Xs = (m == 0) ? sQ : (m == 1) ? sK : sV;
      const u16* Wt = WT + m * 36864 + (ct * 16 + l15) * CEMB + lhi * 8;
      f32x4 z = {0.f, 0.f, 0.f, 0.f};
      #pragma unroll
      for (int rt = 0; rt < 4; ++rt) accv[si][rt] = z;
      #pragma unroll
      for (int ks = 0; ks < 6; ++ks) {
        bf16x8 bw = *reinterpret_cast<const bf16x8*>(Wt + ks * 32);
        #pragma unroll
        for (int rt = 0; rt < 4; ++rt) {
          int row = rt * 16 + l15;
          bf16x8 ax = *reinterpret_cast<const bf16x8*>(Xs + row * ROWB + swz(row, ks * 64 + lhi * 16));
          accv[si][rt] = __builtin_amdgcn_mfma_f32_16x16x32_bf16(ax, bw, accv[si][rt], 0, 0, 0);
        }
      }
    }
  }
  __syncthreads();   // all reads of staged q,k,v done

  #pragma unroll
  for (int si = 0; si < 5; ++si) {
    int strip = wave + si * 8;
    if (strip < 36) {
      int m  = strip / 12;
      int ct = strip - m * 12;
      int n  = ct * 16 + l15;
      float bval = ((m == 0) ? bq : (m == 1) ? bk : bv)[n];
      if (m == 0) {
        #pragma unroll
        for (int rt = 0; rt < 4; ++rt)
          #pragma unroll
          for (int r = 0; r < 4; ++r) {
            int row = rt * 16 + lhi * 4 + r;
            *reinterpret_cast<u16*>(sQ + row * ROWB + swz(row, n * 2)) = f2b((accv[si][rt][r] + bval) * scale);
          }
      } else if (m == 1) {
        #pragma unroll
        for (int rt = 0; rt < 4; ++rt)
          #pragma unroll
          for (int r = 0; r < 4; ++r) {
            int row = rt * 16 + lhi * 4 + r;
            *reinterpret_cast<u16*>(sK + row * ROWB + swz(row, n * 2)) = f2b(accv[si][rt][r] + bval);
          }
      } else {   // vhT[chan n][token], 4 consecutive tokens packed per write
        #pragma unroll
        for (int rt = 0; rt < 4; ++rt) {
          int t0 = rt * 16 + lhi * 4;
          u16x4 pk;
          #pragma unroll
          for (int r = 0; r < 4; ++r) pk[r] = f2b(accv[si][rt][r] + bval);
          *reinterpret_cast<u16x4*>(sV + n * VROWB + swz(n, t0 * 2)) = pk;
        }
      }
    }
  }
  __syncthreads();   // qh/kh/vhT ready

  // ---- Phase 3: per (head, row-tile) unit ----
  const float* maskw = maskg + (size_t)(b & 1023) * 4096;
  #pragma unroll
  for (int ui = 0; ui < 3; ++ui) {
    int u  = wave + ui * 8;        // 0..23
    int h  = u >> 2;
    int rt = u & 3;
    int irow = rt * 16 + lhi * 4;  // + r

    // prefetch bias + mask (L2/L3) before MFMAs
    const float* rbp = rb + h * 4096 + irow * 64 + l15;
    const float* mkp = maskw + irow * 64 + l15;
    float rbv[4][4], mkv[4][4];
    #pragma unroll
    for (int ct = 0; ct < 4; ++ct)
      #pragma unroll
      for (int r = 0; r < 4; ++r) {
        rbv[ct][r] = rbp[r * 64 + ct * 16];
        mkv[ct][r] = mkp[r * 64 + ct * 16];
      }

    // S = qh @ kh^T  (K = 32)
    int qrow = rt * 16 + l15;
    bf16x8 aq = *reinterpret_cast<const bf16x8*>(sQ + qrow * ROWB + swz(qrow, h * 64 + lhi * 16));
    f32x4 sv[4];
    #pragma unroll
    for (int ct = 0; ct < 4; ++ct) {
      int krow = ct * 16 + l15;
      bf16x8 bkf = *reinterpret_cast<const bf16x8*>(sK + krow * ROWB + swz(krow, h * 64 + lhi * 16));
      f32x4 z = {0.f, 0.f, 0.f, 0.f};
      sv[ct] = __builtin_amdgcn_mfma_f32_16x16x32_bf16(aq, bkf, z, 0, 0, 0);
    }

    float lg[4][4];
    #pragma unroll
    for (int ct = 0; ct < 4; ++ct)
      #pragma unroll
      for (int r = 0; r < 4; ++r)
        lg[ct][r] = sv[ct][r] + rbv[ct][r] + mkv[ct][r];

    // row softmax (row = attention row lhi*4+r; reduce over 16 lanes x 4 ct)
    float pr[4][4];
    #pragma unroll
    for (int r = 0; r < 4; ++r) {
      float mx = fmaxf(fmaxf(lg[0][r], lg[1][r]), fmaxf(lg[2][r], lg[3][r]));
      mx = fmaxf(mx, __shfl_xor(mx, 1));
      mx = fmaxf(mx, __shfl_xor(mx, 2));
      mx = fmaxf(mx, __shfl_xor(mx, 4));
      mx = fmaxf(mx, __shfl_xor(mx, 8));
      float e0 = __expf(lg[0][r] - mx), e1 = __expf(lg[1][r] - mx);
      float e2 = __expf(lg[2][r] - mx), e3 = __expf(lg[3][r] - mx);
      float sum = e0 + e1 + e2 + e3;
      sum += __shfl_xor(sum, 1);
      sum += __shfl_xor(sum, 2);
      sum += __shfl_xor(sum, 4);
      sum += __shfl_xor(sum, 8);
      float inv = 1.0f / sum;
      pr[0][r] = e0 * inv; pr[1][r] = e1 * inv; pr[2][r] = e2 * inv; pr[3][r] = e3 * inv;
    }

    // attn probs to global (fp32)
    float* ap = attn_out + (((size_t)b * NH + h) * NTOK + irow) * NTOK;
    #pragma unroll
    for (int ct = 0; ct < 4; ++ct)
      #pragma unroll
      for (int r = 0; r < 4; ++r)
        ap[r * 64 + ct * 16 + l15] = pr[ct][r];

    // PV in two K=32 halves through 1KB lane-ordered P scratch
    f32x4 xa[2];
    { f32x4 z = {0.f, 0.f, 0.f, 0.f}; xa[0] = z; xa[1] = z; }
    #pragma unroll
    for (int ks = 0; ks < 2; ++ks) {
      #pragma unroll
      for (int c = 0; c < 2; ++c)
        #pragma unroll
        for (int r = 0; r < 4; ++r) {
          int col  = c * 16 + l15;          // k index within half, 0..31
          int kg   = col >> 3;
          int j    = col & 7;
          int prow = lhi * 4 + r;
          *reinterpret_cast<u16*>(sP + ((kg * 16 + prow) * 8 + j) * 2) = f2b(pr[ks * 2 + c][r]);
        }
      // A-frag read: lane-linear, conflict-free (wave in-order LDS: read of
      // half ks completes before half ks+1 writes land)
      bf16x8 apf = *reinterpret_cast<const bf16x8*>(sP + lane * 16);
      #pragma unroll
      for (int ctv = 0; ctv < 2; ++ctv) {
        int vrow = h * 32 + ctv * 16 + l15;
        bf16x8 bvf = *reinterpret_cast<const bf16x8*>(sV + vrow * VROWB + swz(vrow, ks * 64 + lhi * 16));
        xa[ctv] = __builtin_amdgcn_mfma_f32_16x16x32_bf16(apf, bvf, xa[ctv], 0, 0, 0);
      }
    }

    // X written in place over this unit's (rows, head-cols) region of sQ
    #pragma unroll
    for (int ctv = 0; ctv < 2; ++ctv)
      #pragma unroll
      for (int r = 0; r < 4; ++r) {
        int xrow = rt * 16 + lhi * 4 + r;
        int xcol = h * 32 + ctv * 16 + l15;
        *reinterpret_cast<u16*>(sQ + xrow * ROWB + swz(xrow, xcol * 2)) = f2b(xa[ctv][r]);
      }
  }
  __syncthreads();   // X complete

  // ---- Phase 4: out = x @ Wp + bp.  24 units = 12 ct x 2 row-halves ----
  #pragma unroll
  for (int ui = 0; ui < 3; ++ui) {
    int u2 = wave + ui * 8;        // 0..23
    int ct = u2 % 12;
    int rh = u2 / 12;
    const u16* Wt = WT + 3 * 36864 + (ct * 16 + l15) * CEMB + lhi * 8;
    f32x4 oa[2];
    { f32x4 z = {0.f, 0.f, 0.f, 0.f}; oa[0] = z; oa[1] = z; }
    #pragma unroll
    for (int ks = 0; ks < 6; ++ks) {
      bf16x8 bw = *reinterpret_cast<const bf16x8*>(Wt + ks * 32);
      #pragma unroll
      for (int rr = 0; rr < 2; ++rr) {
        int xrow = rh * 32 + rr * 16 + l15;
        bf16x8 ax = *reinterpret_cast<const bf16x8*>(sQ + xrow * ROWB + swz(xrow, ks * 64 + lhi * 16));
        oa[rr] = __builtin_amdgcn_mfma_f32_16x16x32_bf16(ax, bw, oa[rr], 0, 0, 0);
      }
    }
    float bias = bp[ct * 16 + l15];
    #pragma unroll
    for (int rr = 0; rr < 2; ++rr)
      #pragma unroll
      for (int r = 0; r < 4; ++r)
        xout[((size_t)b * NTOK + rh * 32 + rr * 16 + lhi * 4 + r) * CEMB + ct * 16 + l15] = oa[rr][r] + bias;
  }
}

extern "C" void kernel_launch(void* const* d_in, const int* in_sizes, int n_in,
                              void* d_out, int out_size, void* d_ws, size_t ws_size,
                              hipStream_t stream) {
  const float* q    = (const float*)d_in[0];
  const float* k    = (const float*)d_in[1];
  const float* v    = (const float*)d_in[2];
  const float* mask = (const float*)d_in[3];
  const float* Wq   = (const float*)d_in[4];
  const float* bq   = (const float*)d_in[5];
  const float* Wk   = (const float*)d_in[6];
  const float* bk   = (const float*)d_in[7];
  const float* Wv   = (const float*)d_in[8];
  const float* bv   = (const float*)d_in[9];
  const float* Wp   = (const float*)d_in[10];
  const float* bp   = (const float*)d_in[11];
  const float* btab = (const float*)d_in[12];
  const int*   ridx = (const int*)d_in[13];

  u16*   WT = (u16*)d_ws;                               // 4 * 36864 bf16
  float* rb = (float*)((char*)d_ws + 4 * 36864 * 2);    // 6*64*64 fp32

  float* xout = (float*)d_out;
  float* attn = xout + (size_t)2048 * NTOK * CEMB;

  prep_kernel<<<672, 256, 0, stream>>>(Wq, Wk, Wv, Wp, btab, ridx, WT, rb);
  wattn_kernel<<<2048, 512, 0, stream>>>(q, k, v, mask, bq, bk, bv, bp, WT, rb, xout, attn);
}